// Round 3
// baseline (2856.560 us; speedup 1.0000x reference)
//
#include <hip/hip_runtime.h>
#include <stdint.h>

#define FPOFF _Pragma("clang fp contract(off)")

// ---------------- problem sizes ----------------
#define ROWS 8192      // N*Ho*Wo = 8*32*32
#define OC 128
#define NS 5           // subarrays
#define SUB 128
#define LP 640         // NS*SUB (padded L)
#define LREAL 576      // C*kh*kw = 64*9
#define NZ 7           // activation bits
#define NK 3           // weight cells
#define NSLOT 21
#define NPTOT 245760   // 3*128*5*128   probs element count
#define NNTOT 1720320  // 7*3*128*5*128 noise element count

// ---------------- ws layout (bytes) ----------------
#define OFF_HDR      0u          // u32[64]: [0]=xmax_enc, pmin[21]@idx8, pmax[21]@idx32
#define OFF_WSCALE   256u        // f32 [NS][OC]
#define OFF_WQ       4096u       // i8  [OC][LP]
#define OFF_CLS      86016u      // u8  [NK][OC][NS][SUB]
#define OFF_INPUTQ   331776u     // u8  [ROWS][LP]
#define OFF_PACKB    5574656u    // u32 [NZ][ROWS][NS][4]
#define OFF_RQ       10162176u   // f32 [NZ][NK][NS][SUB][OC]
#define OFF_PARTIAL  17043456u   // f32 [NS][ROWS][OC]
#define OFF_OUTD     38014976u   // f32 [ROWS][OC]
#define OFF_OUTACC   42209280u   // f32 [ROWS][OC]  (total ~46.4 MB)

struct U2 { uint32_t x, y; };

__host__ __device__ static inline uint32_t rotl32(uint32_t v, int d){ return (v << d) | (v >> (32 - d)); }

// JAX threefry2x32: 20 rounds, injection every 4. keys (k0,k1), counter (c0,c1).
__host__ __device__ static inline U2 threefry(uint32_t k0, uint32_t k1, uint32_t c0, uint32_t c1){
  uint32_t ks2 = k0 ^ k1 ^ 0x1BD11BDAu;
  uint32_t x0 = c0 + k0, x1 = c1 + k1;
#define TFR(r) { x0 += x1; x1 = rotl32(x1, r); x1 ^= x0; }
  TFR(13) TFR(15) TFR(26) TFR(6)  x0 += k1;  x1 += ks2 + 1u;
  TFR(17) TFR(29) TFR(16) TFR(24) x0 += ks2; x1 += k0 + 2u;
  TFR(13) TFR(15) TFR(26) TFR(6)  x0 += k0;  x1 += k1 + 3u;
  TFR(17) TFR(29) TFR(16) TFR(24) x0 += k1;  x1 += ks2 + 4u;
  TFR(13) TFR(15) TFR(26) TFR(6)  x0 += ks2; x1 += k0 + 5u;
#undef TFR
  U2 r; r.x = x0; r.y = x1; return r;
}

__device__ static inline float u2f(uint32_t b){
  // JAX uniform [0,1): bitcast((bits>>9)|0x3f800000) - 1
  return __uint_as_float((b >> 9) | 0x3F800000u) - 1.0f;
}

// order-preserving float<->uint encode for atomic min/max
__device__ static inline uint32_t encf(float f){
  uint32_t u = __float_as_uint(f);
  return (u & 0x80000000u) ? ~u : (u | 0x80000000u);
}
__device__ static inline float decf(uint32_t e){
  return (e & 0x80000000u) ? __uint_as_float(e & 0x7FFFFFFFu) : __uint_as_float(~e);
}

// XLA/chlo erf_inv f32 (Giles). log1p/sqrt via f64 for correctly-rounded f32.
__device__ static inline float xla_erfinv(float x){
  FPOFF
  float m = x * x;
  float w = -(float)log1p((double)(-m));
  float p;
  if (w < 5.0f){
    w = w - 2.5f;
    p = 2.81022636e-08f;
    p = 3.43273939e-07f  + p * w;
    p = -3.5233877e-06f  + p * w;
    p = -4.39150654e-06f + p * w;
    p = 0.00021858087f   + p * w;
    p = -0.00125372503f  + p * w;
    p = -0.00417768164f  + p * w;
    p = 0.246640727f     + p * w;
    p = 1.50140941f      + p * w;
  } else {
    w = (float)sqrt((double)w) - 3.0f;
    p = -0.000200214257f;
    p = 0.000100950558f  + p * w;
    p = 0.00134934322f   + p * w;
    p = -0.00367342844f  + p * w;
    p = 0.00573950773f   + p * w;
    p = -0.0076224613f   + p * w;
    p = 0.00943887047f   + p * w;
    p = 1.00167406f      + p * w;
    p = 2.83297682f      + p * w;
  }
  return p * x;
}

// ---------------- kernels ----------------

__global__ void k_init(uint32_t* hdr){
  int t = threadIdx.x;
  if (t == 0) hdr[0] = 0u;
  if (t < NSLOT){ hdr[8 + t] = 0xFFFFFFFFu; hdr[32 + t] = 0u; }
}

// two-stage max: per-thread 16 elems -> wave shuffle -> LDS -> 1 atomic/block
// (128 atomics total; previous version did 8192 same-address atomics = 95us)
__global__ void k_xmax(const float* __restrict__ x, uint32_t* hdr){
  __shared__ float red[4];
  int t = threadIdx.x;
  const float4* x4 = (const float4*)x;
  int base = blockIdx.x * 1024 + t;     // 128 blocks * 1024 float4 = 524288 floats
  float m = 0.0f;                        // x >= 0 (uniform[0,1)), padding zeros exist anyway
#pragma unroll
  for (int i = 0; i < 4; ++i){
    float4 v = x4[base + i * 256];
    m = fmaxf(m, fmaxf(fmaxf(v.x, v.y), fmaxf(v.z, v.w)));
  }
  for (int off = 32; off; off >>= 1) m = fmaxf(m, __shfl_down(m, off));
  if ((t & 63) == 0) red[t >> 6] = m;
  __syncthreads();
  if (t == 0){
    m = fmaxf(fmaxf(red[0], red[1]), fmaxf(red[2], red[3]));
    atomicMax(&hdr[0], encf(m));
  }
}

// per (s,o): w_scale = max(|w|,1e-8)/127 ; wq = rint(w/w_scale) as i8
__global__ void k_wq(const float* __restrict__ wt, float* __restrict__ wscale, int8_t* __restrict__ wq){
  FPOFF
  int s = blockIdx.x, o = blockIdx.y, t = threadIdx.x;  // 64 threads
  int l0 = s * SUB + t, l1 = l0 + 64;
  float w0 = (l0 < LREAL) ? wt[o * LREAL + l0] : 0.f;
  float w1 = (l1 < LREAL) ? wt[o * LREAL + l1] : 0.f;
  float m = fmaxf(fabsf(w0), fabsf(w1));
  for (int off = 32; off; off >>= 1) m = fmaxf(m, __shfl_down(m, off));
  m = __shfl(m, 0);
  float ws = fmaxf(m, 1e-8f) / 127.0f;
  if (t == 0) wscale[s * OC + o] = ws;
  wq[o * LP + l0] = (int8_t)(int)rintf(w0 / ws);
  wq[o * LP + l1] = (int8_t)(int)rintf(w1 / ws);
}

// im2col + per-tensor activation quant to u8
__global__ void k_inputq(const float* __restrict__ x, const uint32_t* __restrict__ hdr, uint8_t* __restrict__ iq){
  FPOFF
  int r = blockIdx.x, t = threadIdx.x;
  float a_scale = fmaxf(decf(hdr[0]), 1e-8f) / 127.0f;
  int n = r >> 10, hw = r & 1023, oh = hw >> 5, ow = hw & 31;
  for (int l = t; l < LP; l += 256){
    float val = 0.f;
    if (l < LREAL){
      int c = l / 9, r9 = l - c * 9, ki = r9 / 3, kj = r9 - ki * 3;
      int ih = oh - 1 + ki, iw = ow - 1 + kj;
      if ((unsigned)ih < 32u && (unsigned)iw < 32u)
        val = x[(((n << 6) + c) << 10) + (ih << 5) + iw];
    }
    iq[r * LP + l] = (uint8_t)(int)rintf(val / a_scale);
  }
}

// pack bit z of inputQ into u32 words: packB[z][r][s][w], bit t = j = w*32+t
__global__ void k_pack(const uint8_t* __restrict__ iq, uint32_t* __restrict__ packB){
  int gid = blockIdx.x * 256 + threadIdx.x;
  if (gid >= ROWS * 20) return;
  int r = gid / 20, sw = gid - r * 20;
  const uint4* p4 = (const uint4*)(iq + r * LP + sw * 32);
  uint4 a = p4[0], b2 = p4[1];
  uint32_t wds[8] = {a.x, a.y, a.z, a.w, b2.x, b2.y, b2.z, b2.w};
  uint32_t out[NZ];
#pragma unroll
  for (int z = 0; z < NZ; ++z) out[z] = 0u;
#pragma unroll
  for (int tt = 0; tt < 32; ++tt){
    uint32_t byte = (wds[tt >> 2] >> ((tt & 3) * 8)) & 0xFFu;
#pragma unroll
    for (int z = 0; z < NZ; ++z) out[z] |= ((byte >> z) & 1u) << tt;
  }
#pragma unroll
  for (int z = 0; z < NZ; ++z) packB[(z * ROWS + r) * 20 + sw] = out[z];
}

// SAF classes from uniform(kmask), partitionable threefry: bits[i] = x^y of
// threefry(key, (0, i)). 0 normal / 1 sa0 / 2 sa1
__global__ void k_cls(uint8_t* __restrict__ cls, uint32_t km0, uint32_t km1){
  int i = blockIdx.x * 256 + threadIdx.x;
  if (i >= NPTOT) return;
  U2 r = threefry(km0, km1, 0u, (uint32_t)i);
  float f = u2f(r.x ^ r.y);
  cls[i] = (f < 0.001f) ? 1 : ((f > 0.999f) ? 2 : 0);
}

// rQ[z][k][s][j][o] = SAF(where(sa)) of rem*(1+noise); partitionable bits
__global__ void k_rq(const int8_t* __restrict__ wq, const uint8_t* __restrict__ cls,
                     float* __restrict__ rq, uint32_t kn0, uint32_t kn1){
  FPOFF
  int i = blockIdx.x * 256 + threadIdx.x;
  if (i >= NNTOT) return;
  U2 rr = threefry(kn0, kn1, 0u, (uint32_t)i);
  uint32_t bits = rr.x ^ rr.y;
  // noise flat index [z][k][o][s][j]
  int j = i & 127;
  int t = i >> 7;
  int s = t % 5;
  int t2 = t / 5;
  int o = t2 & 127;
  int t3 = t2 >> 7;
  int k = t3 % 3;
  int z = t3 / 3;
  float f = u2f(bits);
  float u = fmaxf(-0x1.fffffep-1f, f * 2.0f + (-0x1.fffffep-1f));
  float nv = (0x1.6a09e6p+0f * xla_erfinv(u)) * 0.05f;
  int wv = (int)wq[o * LP + s * SUB + j];
  int r0 = wv % 4;  int x1 = (wv - r0) / 4;
  int r1 = x1 % 4;  int x2 = (x1 - r1) / 4;
  int r2 = x2 % 4;
  int rem = (k == 0) ? r0 : ((k == 1) ? r1 : r2);
  float remf = (float)rem;
  float v = remf + remf * nv;
  int c = cls[((k * OC + o) * NS + s) * SUB + j];
  if (c == 1) v = 0.1f;
  else if (c == 2) v = (v > 0.f) ? 1.f : ((v < 0.f) ? -1.f : 0.f);
  rq[(((z * NK + k) * NS + s) * SUB + j) * OC + o] = v;
}

// partial[s][r][o] = sum_j bit(r,j) * rQ[j][o], j strictly ascending (bit-exact
// vs sequential-K gemm). Row bits are wave-uniform -> scalar-pipe masks
// (readfirstlane + s_bfe_i32), vector work = v_and + v_add per 64-MAC group.
__global__ __launch_bounds__(256) void k_mm(const float* __restrict__ rq_slice,
                                            const uint32_t* __restrict__ packB_z,
                                            float* __restrict__ partial,
                                            uint32_t* __restrict__ hdr, int slot){
  __shared__ float rqs[64 * 128];
  __shared__ float red[8];
  int s = blockIdx.y;
  int r0 = blockIdx.x * 32;
  int tid = threadIdx.x;
  int wave = tid >> 6;
  int lane = tid & 63;
  int o = ((wave & 1) << 6) | lane;   // wave0/2: o 0-63, wave1/3: o 64-127
  int rbase = r0 + (wave >> 1) * 16;  // 16 rows per wave, uniform across lanes

  float acc[16];
#pragma unroll
  for (int i2 = 0; i2 < 16; ++i2) acc[i2] = 0.f;

  const float4* src = (const float4*)(rq_slice + s * SUB * OC);
  const uint32_t* pb = packB_z + (size_t)rbase * 20 + s * 4;

  for (int half = 0; half < 2; ++half){
    __syncthreads();
#pragma unroll
    for (int m = 0; m < 8; ++m){
      int idx = m * 256 + tid;
      ((float4*)rqs)[idx] = src[half * 2048 + idx];
    }
    __syncthreads();
#pragma unroll
    for (int w2 = 0; w2 < 2; ++w2){
      int w = half * 2 + w2;
      // wave-uniform bit words -> SGPRs (broadcast load + readfirstlane)
      uint32_t sb[16];
#pragma unroll
      for (int i2 = 0; i2 < 16; ++i2)
        sb[i2] = (uint32_t)__builtin_amdgcn_readfirstlane((int)pb[i2 * 20 + w]);
#pragma unroll
      for (int j = 0; j < 32; ++j){
        float rv = rqs[(w2 * 32 + j) * OC + o];
        uint32_t rbits = __float_as_uint(rv);
#pragma unroll
        for (int i2 = 0; i2 < 16; ++i2){
          int m = __builtin_amdgcn_sbfe((int)sb[i2], j, 1);   // s_bfe_i32: 0 / -1
          acc[i2] += __uint_as_float(rbits & (uint32_t)m);    // +0.0 is exact no-op
        }
      }
    }
  }
  float mn = acc[0], mx = acc[0];
#pragma unroll
  for (int i2 = 0; i2 < 16; ++i2){
    partial[(size_t)(s * ROWS + rbase + i2) * OC + o] = acc[i2];
    mn = fminf(mn, acc[i2]); mx = fmaxf(mx, acc[i2]);
  }
  for (int off = 32; off; off >>= 1){
    mn = fminf(mn, __shfl_down(mn, off));
    mx = fmaxf(mx, __shfl_down(mx, off));
  }
  if (lane == 0){ red[wave] = mn; red[4 + wave] = mx; }
  __syncthreads();
  if (tid == 0){
    mn = fminf(fminf(red[0], red[1]), fminf(red[2], red[3]));
    mx = fmaxf(fmaxf(red[4], red[5]), fmaxf(red[6], red[7]));
    atomicMin(&hdr[8 + slot], encf(mn));
    atomicMax(&hdr[32 + slot], encf(mx));
  }
}

// ADC quant + ws_T scale + subarray sum + z/k accumulation (reference order)
__global__ void k_quant(const float* __restrict__ partial, const float* __restrict__ wscale,
                        const uint32_t* __restrict__ hdr, float* __restrict__ outD,
                        float* __restrict__ outacc, float* __restrict__ out,
                        const float* __restrict__ bias, int z, int k, int slot){
  FPOFF
  int e = blockIdx.x * 256 + threadIdx.x;   // exactly ROWS*OC threads
  int r = e >> 7, o = e & 127;
  float mn = decf(hdr[8 + slot]);
  float mx = decf(hdr[32 + slot]);
  float delta = mx - mn;
  float step = delta * 0.03125f;
  if (!(step > 0.f)) step = 1.0f;
  float pq = 0.f;
#pragma unroll
  for (int s = 0; s < NS; ++s){
    float v = partial[(size_t)(s * ROWS + r) * OC + o];
    float fidx = floorf((v - mn) / step);
    fidx = fminf(fmaxf(fidx, 0.f), 31.f);
    float qv = fidx * step + mn;
    pq = pq + qv * wscale[s * OC + o];
  }
  if (k == 0) outD[e] = pq;
  else if (k == 1) outD[e] = outD[e] + pq * 4.0f;
  else {
    float tt = outD[e] + pq * 16.0f;
    float a_scale = fmaxf(decf(hdr[0]), 1e-8f) / 127.0f;
    float contrib = (tt * (float)(1 << z)) * a_scale;
    if (z == 0) outacc[e] = contrib;
    else if (z < 6) outacc[e] = outacc[e] + contrib;
    else {
      float res = outacc[e] + contrib;
      int n = r >> 10, hw = r & 1023;
      out[(((n << 7) + o) << 10) + hw] = res + bias[o];
    }
  }
}

// ---------------- host ----------------
extern "C" void kernel_launch(void* const* d_in, const int* in_sizes, int n_in,
                              void* d_out, int out_size, void* d_ws, size_t ws_size,
                              hipStream_t stream){
  const float* x    = (const float*)d_in[0];
  const float* wt   = (const float*)d_in[1];
  const float* bias = (const float*)d_in[2];
  float* out = (float*)d_out;
  char* ws = (char*)d_ws;
  uint32_t* hdr    = (uint32_t*)(ws + OFF_HDR);
  float*    wscale = (float*)(ws + OFF_WSCALE);
  int8_t*   wq     = (int8_t*)(ws + OFF_WQ);
  uint8_t*  cls    = (uint8_t*)(ws + OFF_CLS);
  uint8_t*  iq     = (uint8_t*)(ws + OFF_INPUTQ);
  uint32_t* packB  = (uint32_t*)(ws + OFF_PACKB);
  float*    rq     = (float*)(ws + OFF_RQ);
  float*    partial= (float*)(ws + OFF_PARTIAL);
  float*    outD   = (float*)(ws + OFF_OUTD);
  float*    outacc = (float*)(ws + OFF_OUTACC);

  // jax.random.key(42) -> (0,42); partitionable (fold-like) split:
  // kmask = both words of threefry(key,(0,0)); knoise = threefry(key,(0,1))
  U2 p0 = threefry(0u, 42u, 0u, 0u);
  U2 p1 = threefry(0u, 42u, 0u, 1u);
  uint32_t km0 = p0.x, km1 = p0.y, kn0 = p1.x, kn1 = p1.y;

  hipLaunchKernelGGL(k_init,   dim3(1),           dim3(64),  0, stream, hdr);
  hipLaunchKernelGGL(k_xmax,   dim3(128),         dim3(256), 0, stream, x, hdr);
  hipLaunchKernelGGL(k_wq,     dim3(5, 128),      dim3(64),  0, stream, wt, wscale, wq);
  hipLaunchKernelGGL(k_inputq, dim3(8192),        dim3(256), 0, stream, x, hdr, iq);
  hipLaunchKernelGGL(k_pack,   dim3(640),         dim3(256), 0, stream, iq, packB);
  hipLaunchKernelGGL(k_cls,    dim3(NPTOT / 256), dim3(256), 0, stream, cls, km0, km1);
  hipLaunchKernelGGL(k_rq,     dim3(NNTOT / 256), dim3(256), 0, stream, wq, cls, rq, kn0, kn1);

  for (int z = 0; z < NZ; ++z){
    for (int k = 0; k < NK; ++k){
      int slot = z * NK + k;
      const float* rqsl = rq + (size_t)slot * NS * SUB * OC;
      const uint32_t* pbz = packB + (size_t)z * ROWS * 20;
      hipLaunchKernelGGL(k_mm,    dim3(256, 5), dim3(256), 0, stream, rqsl, pbz, partial, hdr, slot);
      hipLaunchKernelGGL(k_quant, dim3(4096),   dim3(256), 0, stream, partial, wscale, hdr,
                         outD, outacc, out, bias, z, k, slot);
    }
  }
}

// Round 4
// 975.025 us; speedup vs baseline: 2.9297x; 2.9297x over previous
//
#include <hip/hip_runtime.h>
#include <stdint.h>

#define FPOFF _Pragma("clang fp contract(off)")

// ---------------- problem sizes ----------------
#define ROWS 8192      // N*Ho*Wo = 8*32*32
#define OC 128
#define NS 5           // subarrays
#define SUB 128
#define LP 640         // NS*SUB (padded L)
#define LREAL 576      // C*kh*kw = 64*9
#define NZ 7           // activation bits
#define NK 3           // weight cells
#define NSLOT 21
#define NPTOT 245760   // 3*128*5*128   probs element count
#define NNTOT 1720320  // 7*3*128*5*128 noise element count

// ---------------- ws layout (bytes) ----------------
#define OFF_HDR      0u          // u32[64]: [0]=xmax_enc, pmin[21]@idx8, pmax[21]@idx32
#define OFF_WSCALE   256u        // f32 [NS][OC]
#define OFF_WQ       4096u       // i8  [OC][LP]
#define OFF_CLS      86016u      // u8  [NK][OC][NS][SUB]
#define OFF_INPUTQ   331776u     // u8  [ROWS][LP]
#define OFF_PACKB    5574656u    // u32 [NZ][ROWS][NS][4]
#define OFF_RQ       10162176u   // f32 [NZ][NK][NS][SUB][OC]
#define OFF_PARTIAL  17043456u   // f32 [NS][ROWS][OC]
#define OFF_OUTD     38014976u   // f32 [ROWS][OC]
#define OFF_OUTACC   42209280u   // f32 [ROWS][OC]  (total ~46.4 MB)

struct U2 { uint32_t x, y; };

__host__ __device__ static inline uint32_t rotl32(uint32_t v, int d){ return (v << d) | (v >> (32 - d)); }

// JAX threefry2x32: 20 rounds, injection every 4. keys (k0,k1), counter (c0,c1).
__host__ __device__ static inline U2 threefry(uint32_t k0, uint32_t k1, uint32_t c0, uint32_t c1){
  uint32_t ks2 = k0 ^ k1 ^ 0x1BD11BDAu;
  uint32_t x0 = c0 + k0, x1 = c1 + k1;
#define TFR(r) { x0 += x1; x1 = rotl32(x1, r); x1 ^= x0; }
  TFR(13) TFR(15) TFR(26) TFR(6)  x0 += k1;  x1 += ks2 + 1u;
  TFR(17) TFR(29) TFR(16) TFR(24) x0 += ks2; x1 += k0 + 2u;
  TFR(13) TFR(15) TFR(26) TFR(6)  x0 += k0;  x1 += k1 + 3u;
  TFR(17) TFR(29) TFR(16) TFR(24) x0 += k1;  x1 += ks2 + 4u;
  TFR(13) TFR(15) TFR(26) TFR(6)  x0 += ks2; x1 += k0 + 5u;
#undef TFR
  U2 r; r.x = x0; r.y = x1; return r;
}

__device__ static inline float u2f(uint32_t b){
  // JAX uniform [0,1): bitcast((bits>>9)|0x3f800000) - 1
  return __uint_as_float((b >> 9) | 0x3F800000u) - 1.0f;
}

// order-preserving float<->uint encode for atomic min/max
__device__ static inline uint32_t encf(float f){
  uint32_t u = __float_as_uint(f);
  return (u & 0x80000000u) ? ~u : (u | 0x80000000u);
}
__device__ static inline float decf(uint32_t e){
  return (e & 0x80000000u) ? __uint_as_float(e & 0x7FFFFFFFu) : __uint_as_float(~e);
}

// XLA/chlo erf_inv f32 (Giles). log1p/sqrt via f64 for correctly-rounded f32.
__device__ static inline float xla_erfinv(float x){
  FPOFF
  float m = x * x;
  float w = -(float)log1p((double)(-m));
  float p;
  if (w < 5.0f){
    w = w - 2.5f;
    p = 2.81022636e-08f;
    p = 3.43273939e-07f  + p * w;
    p = -3.5233877e-06f  + p * w;
    p = -4.39150654e-06f + p * w;
    p = 0.00021858087f   + p * w;
    p = -0.00125372503f  + p * w;
    p = -0.00417768164f  + p * w;
    p = 0.246640727f     + p * w;
    p = 1.50140941f      + p * w;
  } else {
    w = (float)sqrt((double)w) - 3.0f;
    p = -0.000200214257f;
    p = 0.000100950558f  + p * w;
    p = 0.00134934322f   + p * w;
    p = -0.00367342844f  + p * w;
    p = 0.00573950773f   + p * w;
    p = -0.0076224613f   + p * w;
    p = 0.00943887047f   + p * w;
    p = 1.00167406f      + p * w;
    p = 2.83297682f      + p * w;
  }
  return p * x;
}

// ---------------- kernels ----------------

__global__ void k_init(uint32_t* hdr){
  int t = threadIdx.x;
  if (t == 0) hdr[0] = 0u;
  if (t < NSLOT){ hdr[8 + t] = 0xFFFFFFFFu; hdr[32 + t] = 0u; }
}

// two-stage max: per-thread 16 elems -> wave shuffle -> LDS -> 1 atomic/block
__global__ void k_xmax(const float* __restrict__ x, uint32_t* hdr){
  __shared__ float red[4];
  int t = threadIdx.x;
  const float4* x4 = (const float4*)x;
  int base = blockIdx.x * 1024 + t;     // 128 blocks * 1024 float4 = 524288 floats
  float m = 0.0f;                        // x >= 0 (uniform[0,1))
#pragma unroll
  for (int i = 0; i < 4; ++i){
    float4 v = x4[base + i * 256];
    m = fmaxf(m, fmaxf(fmaxf(v.x, v.y), fmaxf(v.z, v.w)));
  }
  for (int off = 32; off; off >>= 1) m = fmaxf(m, __shfl_down(m, off));
  if ((t & 63) == 0) red[t >> 6] = m;
  __syncthreads();
  if (t == 0){
    m = fmaxf(fmaxf(red[0], red[1]), fmaxf(red[2], red[3]));
    atomicMax(&hdr[0], encf(m));
  }
}

// per (s,o): w_scale = max(|w|,1e-8)/127 ; wq = rint(w/w_scale) as i8
__global__ void k_wq(const float* __restrict__ wt, float* __restrict__ wscale, int8_t* __restrict__ wq){
  FPOFF
  int s = blockIdx.x, o = blockIdx.y, t = threadIdx.x;  // 64 threads
  int l0 = s * SUB + t, l1 = l0 + 64;
  float w0 = (l0 < LREAL) ? wt[o * LREAL + l0] : 0.f;
  float w1 = (l1 < LREAL) ? wt[o * LREAL + l1] : 0.f;
  float m = fmaxf(fabsf(w0), fabsf(w1));
  for (int off = 32; off; off >>= 1) m = fmaxf(m, __shfl_down(m, off));
  m = __shfl(m, 0);
  float ws = fmaxf(m, 1e-8f) / 127.0f;
  if (t == 0) wscale[s * OC + o] = ws;
  wq[o * LP + l0] = (int8_t)(int)rintf(w0 / ws);
  wq[o * LP + l1] = (int8_t)(int)rintf(w1 / ws);
}

// im2col + per-tensor activation quant to u8
__global__ void k_inputq(const float* __restrict__ x, const uint32_t* __restrict__ hdr, uint8_t* __restrict__ iq){
  FPOFF
  int r = blockIdx.x, t = threadIdx.x;
  float a_scale = fmaxf(decf(hdr[0]), 1e-8f) / 127.0f;
  int n = r >> 10, hw = r & 1023, oh = hw >> 5, ow = hw & 31;
  for (int l = t; l < LP; l += 256){
    float val = 0.f;
    if (l < LREAL){
      int c = l / 9, r9 = l - c * 9, ki = r9 / 3, kj = r9 - ki * 3;
      int ih = oh - 1 + ki, iw = ow - 1 + kj;
      if ((unsigned)ih < 32u && (unsigned)iw < 32u)
        val = x[(((n << 6) + c) << 10) + (ih << 5) + iw];
    }
    iq[r * LP + l] = (uint8_t)(int)rintf(val / a_scale);
  }
}

// pack bit z of inputQ into u32 words: packB[z][r][s][w], bit t = j = w*32+t
__global__ void k_pack(const uint8_t* __restrict__ iq, uint32_t* __restrict__ packB){
  int gid = blockIdx.x * 256 + threadIdx.x;
  if (gid >= ROWS * 20) return;
  int r = gid / 20, sw = gid - r * 20;
  const uint4* p4 = (const uint4*)(iq + r * LP + sw * 32);
  uint4 a = p4[0], b2 = p4[1];
  uint32_t wds[8] = {a.x, a.y, a.z, a.w, b2.x, b2.y, b2.z, b2.w};
  uint32_t out[NZ];
#pragma unroll
  for (int z = 0; z < NZ; ++z) out[z] = 0u;
#pragma unroll
  for (int tt = 0; tt < 32; ++tt){
    uint32_t byte = (wds[tt >> 2] >> ((tt & 3) * 8)) & 0xFFu;
#pragma unroll
    for (int z = 0; z < NZ; ++z) out[z] |= ((byte >> z) & 1u) << tt;
  }
#pragma unroll
  for (int z = 0; z < NZ; ++z) packB[(z * ROWS + r) * 20 + sw] = out[z];
}

// SAF classes from uniform(kmask), partitionable threefry: bits[i] = x^y of
// threefry(key, (0, i)). 0 normal / 1 sa0 / 2 sa1
__global__ void k_cls(uint8_t* __restrict__ cls, uint32_t km0, uint32_t km1){
  int i = blockIdx.x * 256 + threadIdx.x;
  if (i >= NPTOT) return;
  U2 r = threefry(km0, km1, 0u, (uint32_t)i);
  float f = u2f(r.x ^ r.y);
  cls[i] = (f < 0.001f) ? 1 : ((f > 0.999f) ? 2 : 0);
}

// rQ[z][k][s][j][o] = SAF(where(sa)) of rem*(1+noise); partitionable bits
__global__ void k_rq(const int8_t* __restrict__ wq, const uint8_t* __restrict__ cls,
                     float* __restrict__ rq, uint32_t kn0, uint32_t kn1){
  FPOFF
  int i = blockIdx.x * 256 + threadIdx.x;
  if (i >= NNTOT) return;
  U2 rr = threefry(kn0, kn1, 0u, (uint32_t)i);
  uint32_t bits = rr.x ^ rr.y;
  // noise flat index [z][k][o][s][j]
  int j = i & 127;
  int t = i >> 7;
  int s = t % 5;
  int t2 = t / 5;
  int o = t2 & 127;
  int t3 = t2 >> 7;
  int k = t3 % 3;
  int z = t3 / 3;
  float f = u2f(bits);
  float u = fmaxf(-0x1.fffffep-1f, f * 2.0f + (-0x1.fffffep-1f));
  float nv = (0x1.6a09e6p+0f * xla_erfinv(u)) * 0.05f;
  int wv = (int)wq[o * LP + s * SUB + j];
  int r0 = wv % 4;  int x1 = (wv - r0) / 4;
  int r1 = x1 % 4;  int x2 = (x1 - r1) / 4;
  int r2 = x2 % 4;
  int rem = (k == 0) ? r0 : ((k == 1) ? r1 : r2);
  float remf = (float)rem;
  float v = remf + remf * nv;
  int c = cls[((k * OC + o) * NS + s) * SUB + j];
  if (c == 1) v = 0.1f;
  else if (c == 2) v = (v > 0.f) ? 1.f : ((v < 0.f) ? -1.f : 0.f);
  rq[(((z * NK + k) * NS + s) * SUB + j) * OC + o] = v;
}

// partial[s][r][o] = sum_j bit(r,j) * rQ[j][o], j=0..127 strictly ascending.
// Lanes = rows (per-lane bit words, 2 VALU per j amortized over 16 o's);
// rQ[j][o-tile] via wave-uniform scalar loads (SGPRs); inner op = v_fmac
// acc, s, v (1 VALU/MAC, bit-exact: fma(1,rv,acc)=add, fma(0,rv,acc)=acc).
__global__ __launch_bounds__(256) void k_mm(const float* __restrict__ rq_slice,
                                            const uint32_t* __restrict__ packB_z,
                                            float* __restrict__ partial,
                                            uint32_t* __restrict__ hdr, int slot){
  FPOFF
  __shared__ float red[8];
  int s = blockIdx.z;
  int tid = threadIdx.x;
  int wave = tid >> 6;
  int lane = tid & 63;
  int r = blockIdx.x * 64 + lane;                 // lane = row
  int o0 = __builtin_amdgcn_readfirstlane(blockIdx.y * 64 + wave * 16);  // uniform o-tile

  // per-lane bit words for this (z-slice, row, s): 4 contiguous u32
  const uint4* pb = (const uint4*)(packB_z + (size_t)r * 20 + s * 4);
  uint4 bw4 = pb[0];
  uint32_t bw[4] = {bw4.x, bw4.y, bw4.z, bw4.w};

  const float* rvbase = rq_slice + (size_t)s * SUB * OC + o0;  // uniform

  float acc[16];
#pragma unroll
  for (int i2 = 0; i2 < 16; ++i2) acc[i2] = 0.f;

#pragma unroll
  for (int w = 0; w < 4; ++w){
#pragma unroll
    for (int j = 0; j < 32; ++j){
      // bit -> 0.0f / 1.0f : v_bfe_i32 + v_and (2 VALU, amortized over 16 o)
      int msk = ((int)(bw[w] << (31 - j))) >> 31;
      float bitf = __uint_as_float((uint32_t)msk & 0x3F800000u);
      const float* p = rvbase + (w * 32 + j) * OC;   // uniform -> s_load
#pragma unroll
      for (int i2 = 0; i2 < 16; ++i2)
        acc[i2] = __builtin_fmaf(p[i2], bitf, acc[i2]);   // v_fmac acc, s, v
    }
  }

  // store 16 consecutive o per lane (4x float4, 64B contiguous per lane)
  float4* pst = (float4*)(partial + (size_t)(s * ROWS + r) * OC + o0);
  pst[0] = make_float4(acc[0], acc[1], acc[2], acc[3]);
  pst[1] = make_float4(acc[4], acc[5], acc[6], acc[7]);
  pst[2] = make_float4(acc[8], acc[9], acc[10], acc[11]);
  pst[3] = make_float4(acc[12], acc[13], acc[14], acc[15]);

  float mn = acc[0], mx = acc[0];
#pragma unroll
  for (int i2 = 1; i2 < 16; ++i2){ mn = fminf(mn, acc[i2]); mx = fmaxf(mx, acc[i2]); }
  for (int off = 32; off; off >>= 1){
    mn = fminf(mn, __shfl_down(mn, off));
    mx = fmaxf(mx, __shfl_down(mx, off));
  }
  if (lane == 0){ red[wave] = mn; red[4 + wave] = mx; }
  __syncthreads();
  if (tid == 0){
    mn = fminf(fminf(red[0], red[1]), fminf(red[2], red[3]));
    mx = fmaxf(fmaxf(red[4], red[5]), fmaxf(red[6], red[7]));
    atomicMin(&hdr[8 + slot], encf(mn));
    atomicMax(&hdr[32 + slot], encf(mx));
  }
}

// ADC quant + ws_T scale + subarray sum + z/k accumulation (reference order)
__global__ void k_quant(const float* __restrict__ partial, const float* __restrict__ wscale,
                        const uint32_t* __restrict__ hdr, float* __restrict__ outD,
                        float* __restrict__ outacc, float* __restrict__ out,
                        const float* __restrict__ bias, int z, int k, int slot){
  FPOFF
  int e = blockIdx.x * 256 + threadIdx.x;   // exactly ROWS*OC threads
  int r = e >> 7, o = e & 127;
  float mn = decf(hdr[8 + slot]);
  float mx = decf(hdr[32 + slot]);
  float delta = mx - mn;
  float step = delta * 0.03125f;
  if (!(step > 0.f)) step = 1.0f;
  float pq = 0.f;
#pragma unroll
  for (int s = 0; s < NS; ++s){
    float v = partial[(size_t)(s * ROWS + r) * OC + o];
    float fidx = floorf((v - mn) / step);
    fidx = fminf(fmaxf(fidx, 0.f), 31.f);
    float qv = fidx * step + mn;
    pq = pq + qv * wscale[s * OC + o];
  }
  if (k == 0) outD[e] = pq;
  else if (k == 1) outD[e] = outD[e] + pq * 4.0f;
  else {
    float tt = outD[e] + pq * 16.0f;
    float a_scale = fmaxf(decf(hdr[0]), 1e-8f) / 127.0f;
    float contrib = (tt * (float)(1 << z)) * a_scale;
    if (z == 0) outacc[e] = contrib;
    else if (z < 6) outacc[e] = outacc[e] + contrib;
    else {
      float res = outacc[e] + contrib;
      int n = r >> 10, hw = r & 1023;
      out[(((n << 7) + o) << 10) + hw] = res + bias[o];
    }
  }
}

// ---------------- host ----------------
extern "C" void kernel_launch(void* const* d_in, const int* in_sizes, int n_in,
                              void* d_out, int out_size, void* d_ws, size_t ws_size,
                              hipStream_t stream){
  const float* x    = (const float*)d_in[0];
  const float* wt   = (const float*)d_in[1];
  const float* bias = (const float*)d_in[2];
  float* out = (float*)d_out;
  char* ws = (char*)d_ws;
  uint32_t* hdr    = (uint32_t*)(ws + OFF_HDR);
  float*    wscale = (float*)(ws + OFF_WSCALE);
  int8_t*   wq     = (int8_t*)(ws + OFF_WQ);
  uint8_t*  cls    = (uint8_t*)(ws + OFF_CLS);
  uint8_t*  iq     = (uint8_t*)(ws + OFF_INPUTQ);
  uint32_t* packB  = (uint32_t*)(ws + OFF_PACKB);
  float*    rq     = (float*)(ws + OFF_RQ);
  float*    partial= (float*)(ws + OFF_PARTIAL);
  float*    outD   = (float*)(ws + OFF_OUTD);
  float*    outacc = (float*)(ws + OFF_OUTACC);

  // jax.random.key(42) -> (0,42); partitionable (fold-like) split:
  // kmask = both words of threefry(key,(0,0)); knoise = threefry(key,(0,1))
  U2 p0 = threefry(0u, 42u, 0u, 0u);
  U2 p1 = threefry(0u, 42u, 0u, 1u);
  uint32_t km0 = p0.x, km1 = p0.y, kn0 = p1.x, kn1 = p1.y;

  hipLaunchKernelGGL(k_init,   dim3(1),           dim3(64),  0, stream, hdr);
  hipLaunchKernelGGL(k_xmax,   dim3(128),         dim3(256), 0, stream, x, hdr);
  hipLaunchKernelGGL(k_wq,     dim3(5, 128),      dim3(64),  0, stream, wt, wscale, wq);
  hipLaunchKernelGGL(k_inputq, dim3(8192),        dim3(256), 0, stream, x, hdr, iq);
  hipLaunchKernelGGL(k_pack,   dim3(640),         dim3(256), 0, stream, iq, packB);
  hipLaunchKernelGGL(k_cls,    dim3(NPTOT / 256), dim3(256), 0, stream, cls, km0, km1);
  hipLaunchKernelGGL(k_rq,     dim3(NNTOT / 256), dim3(256), 0, stream, wq, cls, rq, kn0, kn1);

  for (int z = 0; z < NZ; ++z){
    for (int k = 0; k < NK; ++k){
      int slot = z * NK + k;
      const float* rqsl = rq + (size_t)slot * NS * SUB * OC;
      const uint32_t* pbz = packB + (size_t)z * ROWS * 20;
      hipLaunchKernelGGL(k_mm,    dim3(128, 2, 5), dim3(256), 0, stream, rqsl, pbz, partial, hdr, slot);
      hipLaunchKernelGGL(k_quant, dim3(4096),      dim3(256), 0, stream, partial, wscale, hdr,
                         outD, outacc, out, bias, z, k, slot);
    }
  }
}